// Round 5
// baseline (241.471 us; speedup 1.0000x reference)
//
#include <hip/hip_runtime.h>
#include <hip/hip_bf16.h>
#include <hip/hip_fp16.h>

#define BATCH 8
#define NSEQ 1024
#define DIMM 448
#define NHEAD 7
#define HDIM 64
#define MROWS (BATCH*NSEQ)   // 8192
#define KDIM 448
#define SCALE_F 0.125f
// 0.125 * log2(e): folded into Q (gemm1 epilogue) and bias (prep) so the
// softmax inner loop is a bare v_exp_f32 (exp2).
#define QB_SC 0.18033688011112042f

typedef short short8 __attribute__((ext_vector_type(8)));
typedef float floatx16 __attribute__((ext_vector_type(16)));

#define MFMA32(a,b,c) __builtin_amdgcn_mfma_f32_32x32x16_bf16(a,b,c,0,0,0)

__device__ __forceinline__ unsigned short f2bf(float f){
    __hip_bfloat16 h = __float2bfloat16(f);
    return *reinterpret_cast<unsigned short*>(&h);
}
__device__ __forceinline__ float bf2f(unsigned short u){
    __hip_bfloat16 h; *reinterpret_cast<unsigned short*>(&h) = u;
    return __bfloat162float(h);
}

// ---------------------------------------------------------------------------
// prep_all: fused conversions (one launch).
//   [0,3584)      : x fp32 -> xh bf16 (1 float4/thread)
//   [3584,4032)   : ek fp32 -> ekh bf16
//   [4032,4228)   : wqv [448][896] -> wqvTh [896][448] bf16  (4x 64-thr units)
//   [4228,4340)   : wout [448][448] -> woTh/woTl [512][448] split bf16
//   [4340,6132)   : eb -> bp32 f32, pre-scaled by 0.125*log2e, stored in
//                   MFMA C-fragment granule order (4x 64-thr units per block)
// bp32 layout: ((h*32 + qt2)*32 + mt)*1024 + lane*16 + r  where the value is
//   eb[h][qt2*32 + (lane&31)][mt*32 + (r&3)+8*(r>>2)+4*(lane>>5)] * QB_SC
//   i.e. exactly the C/D fragment of S = MFMA32(K, Q) for that (qt2, mt).
// ---------------------------------------------------------------------------
__global__ __launch_bounds__(256)
void prep_all(const float* __restrict__ x, const float* __restrict__ ek,
              const float* __restrict__ wqv, const float* __restrict__ wout,
              const float* __restrict__ eb,
              unsigned short* __restrict__ xh, unsigned short* __restrict__ ekh,
              unsigned short* __restrict__ wqvTh, unsigned short* __restrict__ woTh,
              unsigned short* __restrict__ woTl, float* __restrict__ bp32)
{
    __shared__ float T[4][32][33];
    const int bx = blockIdx.x, tid = threadIdx.x;

    if (bx < 3584) {                         // x -> bf16
        int i = bx*256 + tid;
        float4 v = ((const float4*)x)[i];
        ((ushort4*)xh)[i] = make_ushort4(f2bf(v.x), f2bf(v.y), f2bf(v.z), f2bf(v.w));
    } else if (bx < 4032) {                  // ek -> bf16
        int i = (bx-3584)*256 + tid;
        float4 v = ((const float4*)ek)[i];
        ((ushort4*)ekh)[i] = make_ushort4(f2bf(v.x), f2bf(v.y), f2bf(v.z), f2bf(v.w));
    } else if (bx < 4228) {                  // wqv transpose, single bf16
        int lid = (bx-4032)*4 + (tid>>6);    // 0..783 = kc(56) x ng(14)
        int kc = lid % 56, ng = lid / 56;
        int n = ng*64 + (tid&63);
        unsigned short h[8];
#pragma unroll
        for (int j = 0; j < 8; ++j) h[j] = f2bf(wqv[(size_t)(kc*8+j)*896 + n]);
        size_t o = (size_t)n*KDIM + kc*8;
        *(ushort4*)(wqvTh + o)     = make_ushort4(h[0],h[1],h[2],h[3]);
        *(ushort4*)(wqvTh + o + 4) = make_ushort4(h[4],h[5],h[6],h[7]);
    } else if (bx < 4340) {                  // wout transpose, split hi/lo
        int lid = (bx-4228)*4 + (tid>>6);    // 0..447 = kc(56) x ng(8)
        int kc = lid % 56, ng = lid / 56;
        int n = ng*64 + (tid&63);
        ushort4 h0={0,0,0,0}, h1={0,0,0,0}, l0={0,0,0,0}, l1={0,0,0,0};
        if (n < DIMM) {
            unsigned short h[8], l[8];
#pragma unroll
            for (int j = 0; j < 8; ++j) {
                float f = wout[(size_t)(kc*8+j)*DIMM + n];
                h[j] = f2bf(f); l[j] = f2bf(f - bf2f(h[j]));
            }
            h0 = make_ushort4(h[0],h[1],h[2],h[3]); h1 = make_ushort4(h[4],h[5],h[6],h[7]);
            l0 = make_ushort4(l[0],l[1],l[2],l[3]); l1 = make_ushort4(l[4],l[5],l[6],l[7]);
        }
        size_t o = (size_t)n*KDIM + kc*8;
        *(ushort4*)(woTh + o) = h0; *(ushort4*)(woTh + o + 4) = h1;
        *(ushort4*)(woTl + o) = l0; *(ushort4*)(woTl + o + 4) = l1;
    } else {                                 // bias prep -> f32 fragment order
        const int su = tid >> 6, lane = tid & 63;
        const int lid = (bx-4340)*4 + su;    // 0..7167 = (h, qt2, mt)
        const int mt = lid & 31, qt2 = (lid>>5) & 31, h = lid >> 10;
        const int qr = lane >> 1, hf = lane & 1;
        const float* src = eb + ((size_t)(h*NSEQ) + qt2*32 + qr)*NSEQ + mt*32 + hf*16;
#pragma unroll
        for (int j = 0; j < 4; ++j) {
            float4 v = *(const float4*)(src + j*4);
            T[su][qr][hf*16 + j*4+0] = v.x;  T[su][qr][hf*16 + j*4+1] = v.y;
            T[su][qr][hf*16 + j*4+2] = v.z;  T[su][qr][hf*16 + j*4+3] = v.w;
        }
        __syncthreads();
        const int lq = lane & 31, quad = lane >> 5;
        float* dst = bp32 + ((size_t)((h*32 + qt2)*32 + mt))*1024 + lane*16;
        float o[16];
#pragma unroll
        for (int r = 0; r < 16; ++r) {
            const int m = (r&3) + 8*(r>>2) + 4*quad;
            o[r] = T[su][lq][m] * QB_SC;
        }
#pragma unroll
        for (int u = 0; u < 4; ++u)
            *(float4*)(dst + u*4) = make_float4(o[u*4],o[u*4+1],o[u*4+2],o[u*4+3]);
    }
}

// ---------------------------------------------------------------------------
// gemm1_reg: qv = x @ w_qv, single bf16, REGISTER-ONLY (no LDS, no barriers).
// 1 wave per block, tile 64x64, BK=32, depth-1 reg prefetch.
// grid (128, 14), block 64. y<7 -> q heads (PRE-SCALED by 0.125*log2e for
// the exp2-folded softmax); y>=7 -> vT heads (transposed, unscaled).
// ---------------------------------------------------------------------------
__global__ __launch_bounds__(64, 2)
void gemm1_reg(const unsigned short* __restrict__ Ah, const unsigned short* __restrict__ Bh,
               unsigned short* __restrict__ qd, unsigned short* __restrict__ vTd)
{
    const int lane = threadIdx.x;
    const int lq = lane & 31, lh = lane >> 5;
    const int m0 = blockIdx.x * 64;
    const int y  = blockIdx.y;
    const int n0 = y * 64;
    const unsigned short* aB = Ah + (size_t)(m0 + lq)*KDIM + lh*8;
    const unsigned short* bB = Bh + (size_t)(n0 + lq)*KDIM + lh*8;

    floatx16 acc[2][2] = {};
    short8 aR[2][2][2], bR[2][2][2];
#define LD1(kt, par) {                                                        \
    _Pragma("unroll") for (int fm = 0; fm < 2; ++fm)                          \
    _Pragma("unroll") for (int c = 0; c < 2; ++c) {                           \
        aR[par][fm][c] = *(const short8*)(aB + (size_t)fm*32*KDIM + (kt)*32 + c*16); \
        bR[par][fm][c] = *(const short8*)(bB + (size_t)fm*32*KDIM + (kt)*32 + c*16); } }

    LD1(0, 0)
#pragma unroll
    for (int kt = 0; kt < 14; ++kt) {
        const int par = kt & 1;
        if (kt < 13) LD1(kt+1, par^1)
#pragma unroll
        for (int c = 0; c < 2; ++c)
#pragma unroll
            for (int fm = 0; fm < 2; ++fm)
#pragma unroll
                for (int fn = 0; fn < 2; ++fn)
                    acc[fm][fn] = MFMA32(aR[par][fm][c], bR[par][fn][c], acc[fm][fn]);
    }
#undef LD1

    if (y < NHEAD) {
#pragma unroll
        for (int fm = 0; fm < 2; ++fm)
#pragma unroll
            for (int fn = 0; fn < 2; ++fn) {
                const int d = fn*32 + lq;
#pragma unroll
                for (int r = 0; r < 16; ++r) {
                    const int gm = m0 + fm*32 + (r&3) + 8*(r>>2) + 4*lh;
                    const int b = gm >> 10, ns = gm & 1023;
                    qd[((size_t)((b*NHEAD + y)*NSEQ + ns))*HDIM + d] = f2bf(acc[fm][fn][r] * QB_SC);
                }
            }
    } else {
        const int head = y - NHEAD;
#pragma unroll
        for (int fm = 0; fm < 2; ++fm)
#pragma unroll
            for (int fn = 0; fn < 2; ++fn) {
                const int d = fn*32 + lq;
#pragma unroll
                for (int r = 0; r < 16; ++r) {
                    const int gm = m0 + fm*32 + (r&3) + 8*(r>>2) + 4*lh;
                    const int b = gm >> 10, ns = gm & 1023;
                    vTd[((size_t)((b*NHEAD + head)*HDIM + d))*NSEQ + ns] = f2bf(acc[fm][fn][r]);
                }
            }
    }
}

// ---------------------------------------------------------------------------
// attn8: flash attention, q-split + b-sharing + bias-as-accumulator.
// 4 waves/block, all same (head, qt2), wave w = batch bq*4+w -> K and bias
// streams L1-shared across waves (attn7's win, FETCH 43->19 MB). Each wave:
// 32 q-rows, full 32 m-tiles. Per SEC: S initialized from the f32 bias
// fragment (no h2f/fmaf), 4 QK MFMAs, bare v_exp_f32 softmax (scales folded
// into Q and bias), P->LDS transpose (wave-private, no barriers), 4 PV MFMAs.
// Grid 448 = (2 bq, 32 qt2, 7 h) -> every CU has work, most have 2 blocks
// (2 waves/SIMD) to interleave the serial chains that caused attn7's ~70%
// stall (MfmaUtil 12 + VALU 20 + Occ 7.7 at 1 wave/SIMD).
// Bijective XCD swizzle (448 = 8*56).
// ---------------------------------------------------------------------------
__global__ __launch_bounds__(256, 2)
void attn8(const unsigned short* __restrict__ qh_g, const unsigned short* __restrict__ vTh,
           const unsigned short* __restrict__ ekh, const float* __restrict__ bp32,
           unsigned short* __restrict__ aoh, unsigned short* __restrict__ aol)
{
    __shared__ unsigned short pS[4][1024];   // per-wave P transpose (8KB)
    __shared__ float linv[4][32];            // per-wave 1/l

    const int tid = threadIdx.x;
    const int w = tid >> 6, lane = tid & 63;
    const int lq = lane & 31, lh = lane >> 5;

    // bijective XCD swizzle: 448 blocks, 56 per XCD (same-h blocks grouped)
    const int orig = blockIdx.x;
    const int wg = (orig & 7)*56 + (orig >> 3);
    const int bq = wg & 1, qt2 = (wg >> 1) & 31, head = wg >> 6;
    const int b = bq*4 + w;
    const int bh = b*NHEAD + head;

    short8 qf[4];
#pragma unroll
    for (int c = 0; c < 4; ++c)
        qf[c] = *(const short8*)(qh_g +
            ((size_t)(bh*NSEQ) + qt2*32 + lq)*HDIM + c*16 + lh*8);

    const unsigned short* kB = ekh + ((size_t)head*NSEQ + lq)*HDIM + lh*8;        // b-indep
    const unsigned short* vB = vTh + ((size_t)(bh*HDIM) + lq)*NSEQ;               // per-b
    const float* bB = bp32 + ((size_t)(head*32 + qt2))*32768 + lane*16;           // b-indep

    short8 kR[2][4], vR[2][4];
    float4 bR[2][4];
#define PREF(J, par) { const int mm = ((J) < 32) ? (J) : 0;                    \
    _Pragma("unroll") for (int c = 0; c < 4; ++c)                              \
        kR[par][c] = *(const short8*)(kB + (size_t)mm*2048 + c*16);            \
    _Pragma("unroll") for (int c2 = 0; c2 < 2; ++c2)                           \
    _Pragma("unroll") for (int h2 = 0; h2 < 2; ++h2)                           \
        vR[par][c2*2+h2] = *(const short8*)(vB + (size_t)(h2*32)*NSEQ + mm*32 + (c2*2+lh)*8); \
    _Pragma("unroll") for (int u = 0; u < 4; ++u)                              \
        bR[par][u] = *(const float4*)(bB + (size_t)mm*1024 + u*4); }

    floatx16 O[2] = {};
    float ls = 0.f;

#define SEC(J, par, nxt) {                                                     \
    PREF((J)+1, nxt)                                                           \
    floatx16 S;                                                                \
    _Pragma("unroll") for (int u = 0; u < 4; ++u) {                            \
        S[u*4+0] = bR[par][u].x; S[u*4+1] = bR[par][u].y;                      \
        S[u*4+2] = bR[par][u].z; S[u*4+3] = bR[par][u].w;                      \
    }                                                                          \
    _Pragma("unroll") for (int c = 0; c < 4; ++c)                              \
        S = MFMA32(kR[par][c], qf[c], S);                                      \
    _Pragma("unroll") for (int g = 0; g < 4; ++g) {                            \
        unsigned short hb[4];                                                  \
        _Pragma("unroll") for (int j2 = 0; j2 < 4; ++j2) {                     \
            const int i = g*4 + j2;                                            \
            float pv = __builtin_amdgcn_exp2f(S[i]);                           \
            ls += pv;  hb[j2] = f2bf(pv);                                      \
        }                                                                      \
        *(ushort4*)(pS[w] + g*256 + lq*8 + lh*4) = make_ushort4(hb[0],hb[1],hb[2],hb[3]); \
    }                                                                          \
    _Pragma("unroll") for (int c2 = 0; c2 < 2; ++c2) {                         \
        short8 pf = *(const short8*)(pS[w] + ((c2*2+lh)*32 + lq)*8);           \
        O[0] = MFMA32(pf, vR[par][c2*2+0], O[0]);                              \
        O[1] = MFMA32(pf, vR[par][c2*2+1], O[1]);                              \
    } }

    PREF(0, 0)
    for (int jj = 0; jj < 16; ++jj) {
        SEC(2*jj,   0, 1)
        SEC(2*jj+1, 1, 0)
    }
#undef SEC
#undef PREF

    // l: partial per lane-column -> full via lh-partner, transpose via LDS
    float lt = ls + __shfl_xor(ls, 32);
    if (lh == 0) linv[w][lq] = 1.f/lt;

#pragma unroll
    for (int r = 0; r < 16; ++r) {
        const int qr = (r&3) + 8*(r>>2) + 4*lh;
        const float inv = linv[w][qr];
        const size_t o = ((size_t)(b*NSEQ) + qt2*32 + qr)*DIMM + head*HDIM + lq;
        float v0 = O[0][r]*inv, v1 = O[1][r]*inv;
        unsigned short h0 = f2bf(v0), h1 = f2bf(v1);
        aoh[o]      = h0;  aol[o]      = f2bf(v0 - bf2f(h0));
        aoh[o + 32] = h1;  aol[o + 32] = f2bf(v1 - bf2f(h1));
    }
}

// ---------------------------------------------------------------------------
// gemm2_reg: out = ao @ w_out + b_out, split-2 (3-term), REGISTER-ONLY.
// 1 wave/block, tile 64x64, BK=32, depth-1 reg prefetch. grid (128, 7).
// ---------------------------------------------------------------------------
__global__ __launch_bounds__(64, 2)
void gemm2_reg(const unsigned short* __restrict__ Ah, const unsigned short* __restrict__ Al,
               const unsigned short* __restrict__ Bh, const unsigned short* __restrict__ Bl,
               const float* __restrict__ bias, float* __restrict__ out)
{
    const int lane = threadIdx.x;
    const int lq = lane & 31, lh = lane >> 5;
    const int m0 = blockIdx.x * 64;
    const int n0 = blockIdx.y * 64;
    const unsigned short* aBh = Ah + (size_t)(m0 + lq)*KDIM + lh*8;
    const unsigned short* aBl = Al + (size_t)(m0 + lq)*KDIM + lh*8;
    const unsigned short* bBh = Bh + (size_t)(n0 + lq)*KDIM + lh*8;
    const unsigned short* bBl = Bl + (size_t)(n0 + lq)*KDIM + lh*8;

    floatx16 acc[2][2] = {};
    short8 aH[2][2][2], aL[2][2][2], bH[2][2][2], bL[2][2][2];
#define LD2(kt, par) {                                                        \
    _Pragma("unroll") for (int fm = 0; fm < 2; ++fm)                          \
    _Pragma("unroll") for (int c = 0; c < 2; ++c) {                           \
        const size_t off = (size_t)fm*32*KDIM + (kt)*32 + c*16;               \
        aH[par][fm][c] = *(const short8*)(aBh + off);                         \
        aL[par][fm][c] = *(const short8*)(aBl + off);                         \
        bH[par][fm][c] = *(const short8*)(bBh + off);                         \
        bL[par][fm][c] = *(const short8*)(bBl + off); } }

    LD2(0, 0)
#pragma unroll
    for (int kt = 0; kt < 14; ++kt) {
        const int par = kt & 1;
        if (kt < 13) LD2(kt+1, par^1)
#pragma unroll
        for (int c = 0; c < 2; ++c)
#pragma unroll
            for (int fm = 0; fm < 2; ++fm)
#pragma unroll
                for (int fn = 0; fn < 2; ++fn) {
                    acc[fm][fn] = MFMA32(aH[par][fm][c], bH[par][fn][c], acc[fm][fn]);
                    acc[fm][fn] = MFMA32(aL[par][fm][c], bH[par][fn][c], acc[fm][fn]);
                    acc[fm][fn] = MFMA32(aH[par][fm][c], bL[par][fn][c], acc[fm][fn]);
                }
    }
#undef LD2

#pragma unroll
    for (int fm = 0; fm < 2; ++fm)
#pragma unroll
        for (int fn = 0; fn < 2; ++fn) {
            const int gn = n0 + fn*32 + lq;
            const float bv = bias[gn];
#pragma unroll
            for (int r = 0; r < 16; ++r) {
                const int gm = m0 + fm*32 + (r&3) + 8*(r>>2) + 4*lh;
                out[(size_t)gm*DIMM + gn] = acc[fm][fn][r] + bv;
            }
        }
}

// ---------------------------------------------------------------------------
extern "C" void kernel_launch(void* const* d_in, const int* in_sizes, int n_in,
                              void* d_out, int out_size, void* d_ws, size_t ws_size,
                              hipStream_t stream)
{
    const float* x    = (const float*)d_in[0];
    const float* wqv  = (const float*)d_in[1];
    const float* ek   = (const float*)d_in[2];
    const float* eb   = (const float*)d_in[3];
    const float* wout = (const float*)d_in[4];
    const float* bout = (const float*)d_in[5];
    float* out = (float*)d_out;

    const size_t MK = (size_t)MROWS*KDIM;        // 3,670,016
    const size_t EK = (size_t)NHEAD*NSEQ*HDIM;   // 458,752
    unsigned short* p = (unsigned short*)d_ws;
    unsigned short* xh    = p;  p += MK;
    unsigned short* wqvTh = p;  p += (size_t)896*KDIM;
    unsigned short* woTh  = p;  p += (size_t)512*KDIM;
    unsigned short* woTl  = p;  p += (size_t)512*KDIM;
    unsigned short* ekh   = p;  p += EK;
    unsigned short* qh    = p;  p += MK;
    unsigned short* vTh   = p;  p += MK;
    float* bp32 = (float*)p;    p += (size_t)2*NHEAD*NSEQ*NSEQ;  // f32 bias
    unsigned short* aoh   = p;  p += MK;
    unsigned short* aol   = p;  p += MK;

    prep_all<<<6132, 256, 0, stream>>>(x, ek, wqv, wout, eb,
                                       xh, ekh, wqvTh, woTh, woTl, bp32);
    gemm1_reg<<<dim3(128, 14), 64, 0, stream>>>(xh, wqvTh, qh, vTh);
    attn8<<<448, 256, 0, stream>>>(qh, vTh, ekh, bp32, aoh, aol);
    gemm2_reg<<<dim3(128, 7), 64, 0, stream>>>(aoh, aol, woTh, woTl, bout, out);
}

// Round 6
// 199.834 us; speedup vs baseline: 1.2084x; 1.2084x over previous
//
#include <hip/hip_runtime.h>
#include <hip/hip_bf16.h>
#include <hip/hip_fp16.h>

#define BATCH 8
#define NSEQ 1024
#define DIMM 448
#define NHEAD 7
#define HDIM 64
#define MROWS (BATCH*NSEQ)   // 8192
#define KDIM 448
#define SCALE_F 0.125f

typedef short short8 __attribute__((ext_vector_type(8)));
typedef float floatx16 __attribute__((ext_vector_type(16)));

#define MFMA32(a,b,c) __builtin_amdgcn_mfma_f32_32x32x16_bf16(a,b,c,0,0,0)

__device__ __forceinline__ unsigned short f2bf(float f){
    __hip_bfloat16 h = __float2bfloat16(f);
    return *reinterpret_cast<unsigned short*>(&h);
}
__device__ __forceinline__ float bf2f(unsigned short u){
    __hip_bfloat16 h; *reinterpret_cast<unsigned short*>(&h) = u;
    return __bfloat162float(h);
}
__device__ __forceinline__ float h2f(unsigned short u){
    __half h; *reinterpret_cast<unsigned short*>(&h) = u;
    return __half2float(h);
}
__device__ __forceinline__ unsigned short f2h(float f){
    __half h = __float2half(f);
    return *reinterpret_cast<unsigned short*>(&h);
}

// ---------------------------------------------------------------------------
// prep_all: fused conversions (one launch).  (identical to the 200.2us run)
//   [0,3584)      : x fp32 -> xh bf16 (1 float4/thread)
//   [3584,4032)   : ek fp32 -> ekh bf16
//   [4032,4228)   : wqv [448][896] -> wqvTh [896][448] bf16  (4x 64-thr units)
//   [4228,4340)   : wout [448][448] -> woTh/woTl [512][448] split bf16
//   [4340,6132)   : eb -> bp fp16, pre-scaled by 0.125, attn granule order
// bp layout: ((((h*16+qt)*32 + mt)*4 + g2*2 + jj)*512 + lane*8 + t) where
//   score q = qt*64 + g2*32 + (lane&31), m = mt*32 + (t&3)+8*(t>>2)+16*jj+4*(lane>>5)
// ---------------------------------------------------------------------------
__global__ __launch_bounds__(256)
void prep_all(const float* __restrict__ x, const float* __restrict__ ek,
              const float* __restrict__ wqv, const float* __restrict__ wout,
              const float* __restrict__ eb,
              unsigned short* __restrict__ xh, unsigned short* __restrict__ ekh,
              unsigned short* __restrict__ wqvTh, unsigned short* __restrict__ woTh,
              unsigned short* __restrict__ woTl, unsigned short* __restrict__ bp)
{
    __shared__ float T[2][64][33];
    const int bx = blockIdx.x, tid = threadIdx.x;

    if (bx < 3584) {                         // x -> bf16
        int i = bx*256 + tid;
        float4 v = ((const float4*)x)[i];
        ((ushort4*)xh)[i] = make_ushort4(f2bf(v.x), f2bf(v.y), f2bf(v.z), f2bf(v.w));
    } else if (bx < 4032) {                  // ek -> bf16
        int i = (bx-3584)*256 + tid;
        float4 v = ((const float4*)ek)[i];
        ((ushort4*)ekh)[i] = make_ushort4(f2bf(v.x), f2bf(v.y), f2bf(v.z), f2bf(v.w));
    } else if (bx < 4228) {                  // wqv transpose, single bf16
        int lid = (bx-4032)*4 + (tid>>6);    // 0..783 = kc(56) x ng(14)
        int kc = lid % 56, ng = lid / 56;
        int n = ng*64 + (tid&63);
        unsigned short h[8];
#pragma unroll
        for (int j = 0; j < 8; ++j) h[j] = f2bf(wqv[(size_t)(kc*8+j)*896 + n]);
        size_t o = (size_t)n*KDIM + kc*8;
        *(ushort4*)(wqvTh + o)     = make_ushort4(h[0],h[1],h[2],h[3]);
        *(ushort4*)(wqvTh + o + 4) = make_ushort4(h[4],h[5],h[6],h[7]);
    } else if (bx < 4340) {                  // wout transpose, split hi/lo
        int lid = (bx-4228)*4 + (tid>>6);    // 0..447 = kc(56) x ng(8)
        int kc = lid % 56, ng = lid / 56;
        int n = ng*64 + (tid&63);
        ushort4 h0={0,0,0,0}, h1={0,0,0,0}, l0={0,0,0,0}, l1={0,0,0,0};
        if (n < DIMM) {
            unsigned short h[8], l[8];
#pragma unroll
            for (int j = 0; j < 8; ++j) {
                float f = wout[(size_t)(kc*8+j)*DIMM + n];
                h[j] = f2bf(f); l[j] = f2bf(f - bf2f(h[j]));
            }
            h0 = make_ushort4(h[0],h[1],h[2],h[3]); h1 = make_ushort4(h[4],h[5],h[6],h[7]);
            l0 = make_ushort4(l[0],l[1],l[2],l[3]); l1 = make_ushort4(l[4],l[5],l[6],l[7]);
        }
        size_t o = (size_t)n*KDIM + kc*8;
        *(ushort4*)(woTh + o) = h0; *(ushort4*)(woTh + o + 4) = h1;
        *(ushort4*)(woTl + o) = l0; *(ushort4*)(woTl + o + 4) = l1;
    } else {                                 // bias prep
        const int sub = tid >> 7, st = tid & 127;
        const int lid = (bx-4340)*2 + sub;   // 0..3583
        const int mt = lid & 31, qt = (lid>>5) & 15, h = lid >> 9;
#pragma unroll
        for (int it = 0; it < 4; ++it) {
            int idx = it*128 + st;
            int row = idx >> 3, c4 = (idx & 7)*4;
            float4 v = *(const float4*)(eb + ((size_t)(h*NSEQ + qt*64 + row))*NSEQ + mt*32 + c4);
            T[sub][row][c4+0]=v.x; T[sub][row][c4+1]=v.y;
            T[sub][row][c4+2]=v.z; T[sub][row][c4+3]=v.w;
        }
        __syncthreads();
        const int g2 = st >> 6, lane = st & 63;
        const int lq = lane & 31, quad = lane >> 5;
        const int q = g2*32 + lq;
        unsigned short* dst = bp + ((((size_t)h*16 + qt)*32 + mt)*4 + g2*2)*512 + lane*8;
#pragma unroll
        for (int jj = 0; jj < 2; ++jj) {
            unsigned short o[8];
#pragma unroll
            for (int t = 0; t < 8; ++t) {
                int m = (t&3) + 8*(t>>2) + 16*jj + 4*quad;
                o[t] = f2h(T[sub][q][m] * SCALE_F);
            }
            *(ushort4*)(dst + jj*512)     = make_ushort4(o[0],o[1],o[2],o[3]);
            *(ushort4*)(dst + jj*512 + 4) = make_ushort4(o[4],o[5],o[6],o[7]);
        }
    }
}

// ---------------------------------------------------------------------------
// gemm1_grp: qv = x @ w_qv, single bf16, REGISTER-ONLY per wave.
// 4 waves per block, all with the SAME n0 (y) and DIFFERENT m0 -> the
// B-tile stream is issued at identical addresses by all 4 waves and hits
// L1 after the first touch (attn7's proven b-sharing mechanism; cache
// traffic 204 -> 128 MB). Per-wave code byte-identical to the proven
// gemm1_reg (128 VGPR, depth-1 ping-pong). grid (32, 14), block 256.
// ---------------------------------------------------------------------------
__global__ __launch_bounds__(256, 2)
void gemm1_grp(const unsigned short* __restrict__ Ah, const unsigned short* __restrict__ Bh,
               unsigned short* __restrict__ qd, unsigned short* __restrict__ vTd)
{
    const int tid = threadIdx.x;
    const int w = tid >> 6, lane = tid & 63;
    const int lq = lane & 31, lh = lane >> 5;
    const int m0 = (blockIdx.x*4 + w) * 64;
    const int y  = blockIdx.y;
    const int n0 = y * 64;
    const unsigned short* aB = Ah + (size_t)(m0 + lq)*KDIM + lh*8;
    const unsigned short* bB = Bh + (size_t)(n0 + lq)*KDIM + lh*8;

    floatx16 acc[2][2] = {};
    short8 aR[2][2][2], bR[2][2][2];
#define LD1(kt, par) {                                                        \
    _Pragma("unroll") for (int fm = 0; fm < 2; ++fm)                          \
    _Pragma("unroll") for (int c = 0; c < 2; ++c) {                           \
        aR[par][fm][c] = *(const short8*)(aB + (size_t)fm*32*KDIM + (kt)*32 + c*16); \
        bR[par][fm][c] = *(const short8*)(bB + (size_t)fm*32*KDIM + (kt)*32 + c*16); } }

    LD1(0, 0)
#pragma unroll
    for (int kt = 0; kt < 14; ++kt) {
        const int par = kt & 1;
        if (kt < 13) LD1(kt+1, par^1)
#pragma unroll
        for (int c = 0; c < 2; ++c)
#pragma unroll
            for (int fm = 0; fm < 2; ++fm)
#pragma unroll
                for (int fn = 0; fn < 2; ++fn)
                    acc[fm][fn] = MFMA32(aR[par][fm][c], bR[par][fn][c], acc[fm][fn]);
    }
#undef LD1

    if (y < NHEAD) {
#pragma unroll
        for (int fm = 0; fm < 2; ++fm)
#pragma unroll
            for (int fn = 0; fn < 2; ++fn) {
                const int d = fn*32 + lq;
#pragma unroll
                for (int r = 0; r < 16; ++r) {
                    const int gm = m0 + fm*32 + (r&3) + 8*(r>>2) + 4*lh;
                    const int b = gm >> 10, ns = gm & 1023;
                    qd[((size_t)((b*NHEAD + y)*NSEQ + ns))*HDIM + d] = f2bf(acc[fm][fn][r]);
                }
            }
    } else {
        const int head = y - NHEAD;
#pragma unroll
        for (int fm = 0; fm < 2; ++fm)
#pragma unroll
            for (int fn = 0; fn < 2; ++fn) {
                const int d = fn*32 + lq;
#pragma unroll
                for (int r = 0; r < 16; ++r) {
                    const int gm = m0 + fm*32 + (r&3) + 8*(r>>2) + 4*lh;
                    const int b = gm >> 10, ns = gm & 1023;
                    vTd[((size_t)((b*NHEAD + head)*HDIM + d))*NSEQ + ns] = f2bf(acc[fm][fn][r]);
                }
            }
    }
}

// ---------------------------------------------------------------------------
// attn7s: attn7 (proven 44.2us) + s_setprio windows around the MFMA
// clusters (T5: +4-7% when independent waves share a CU — attn7 has 4
// independent waves/block, no barriers). Everything else identical:
// 4 waves b-sharing the b-independent K/bias streams through L1, 64 q-rows
// per wave, full 32 m-tiles, depth-1 reg ping-pong, wave-private pS.
// Bijective XCD swizzle (224 = 8*28). grid 224, block 256.
// ---------------------------------------------------------------------------
__global__ __launch_bounds__(256, 2)
void attn7s(const unsigned short* __restrict__ qh_g, const unsigned short* __restrict__ vTh,
            const unsigned short* __restrict__ ekh, const unsigned short* __restrict__ bp,
            unsigned short* __restrict__ aoh, unsigned short* __restrict__ aol)
{
    __shared__ unsigned short pS[4][1024];   // per-wave P transpose (8KB)
    __shared__ float linv[4][2][32];         // per-wave 1/l

    const int tid = threadIdx.x;
    const int w = tid >> 6, lane = tid & 63;
    const int lq = lane & 31, lh = lane >> 5;

    // bijective XCD swizzle: 224 blocks, 28 per XCD
    const int orig = blockIdx.x;
    const int wg = (orig & 7)*28 + (orig >> 3);
    const int bq = wg & 1, qt = (wg >> 1) & 15, head = wg >> 5;
    const int b = bq*4 + w;
    const int bh = b*NHEAD + head;

    short8 qf[2][4];
#pragma unroll
    for (int g2 = 0; g2 < 2; ++g2)
#pragma unroll
        for (int c = 0; c < 4; ++c)
            qf[g2][c] = *(const short8*)(qh_g +
                ((size_t)(bh*NSEQ) + qt*64 + g2*32 + lq)*HDIM + c*16 + lh*8);

    const unsigned short* kB = ekh + ((size_t)head*NSEQ + lq)*HDIM + lh*8;        // b-indep
    const unsigned short* vB = vTh + ((size_t)(bh*HDIM) + lq)*NSEQ;               // per-b
    const unsigned short* bB = bp + ((size_t)(head*16 + qt))*65536 + lane*8;      // b-indep

    short8 kR[2][4], vR[2][4], bR[2][4];
#define PREF(J, par) { const int mm = ((J) < 32) ? (J) : 0;                    \
    _Pragma("unroll") for (int c = 0; c < 4; ++c)                              \
        kR[par][c] = *(const short8*)(kB + (size_t)mm*2048 + c*16);            \
    _Pragma("unroll") for (int c2 = 0; c2 < 2; ++c2)                           \
    _Pragma("unroll") for (int h2 = 0; h2 < 2; ++h2)                           \
        vR[par][c2*2+h2] = *(const short8*)(vB + (size_t)(h2*32)*NSEQ + mm*32 + (c2*2+lh)*8); \
    _Pragma("unroll") for (int u = 0; u < 4; ++u)                              \
        bR[par][u] = *(const short8*)(bB + ((size_t)mm*4 + u)*512); }

    floatx16 O[2][2] = {};
    float ls[2] = {0.f, 0.f};

#define SEC(J, par, nxt) {                                                     \
    PREF((J)+1, nxt)                                                           \
    _Pragma("unroll") for (int g2 = 0; g2 < 2; ++g2) {                         \
        floatx16 S = {};                                                       \
        __builtin_amdgcn_s_setprio(1);                                         \
        _Pragma("unroll") for (int c = 0; c < 4; ++c)                          \
            S = MFMA32(kR[par][c], qf[g2][c], S);                              \
        __builtin_amdgcn_s_setprio(0);                                         \
        _Pragma("unroll") for (int g = 0; g < 4; ++g) {                        \
            unsigned short hb[4];                                              \
            _Pragma("unroll") for (int j2 = 0; j2 < 4; ++j2) {                 \
                const int i = g*4 + j2;                                        \
                float bs = h2f((unsigned short)bR[par][g2*2 + (i>>3)][i&7]);   \
                float pv = __expf(fmaf(S[i], SCALE_F, bs));                    \
                ls[g2] += pv;  hb[j2] = f2bf(pv);                              \
            }                                                                  \
            *(ushort4*)(pS[w] + g*256 + lq*8 + lh*4) = make_ushort4(hb[0],hb[1],hb[2],hb[3]); \
        }                                                                      \
        __builtin_amdgcn_s_setprio(1);                                         \
        _Pragma("unroll") for (int c2 = 0; c2 < 2; ++c2) {                     \
            short8 pf = *(const short8*)(pS[w] + ((c2*2+lh)*32 + lq)*8);       \
            O[g2][0] = MFMA32(pf, vR[par][c2*2+0], O[g2][0]);                  \
            O[g2][1] = MFMA32(pf, vR[par][c2*2+1], O[g2][1]);                  \
        }                                                                      \
        __builtin_amdgcn_s_setprio(0);                                         \
    } }

    PREF(0, 0)
    for (int jj = 0; jj < 16; ++jj) {
        SEC(2*jj,   0, 1)
        SEC(2*jj+1, 1, 0)
    }
#undef SEC
#undef PREF

    // l: partial per lane-column -> full via lh-partner, transpose via LDS
    float lt0 = ls[0] + __shfl_xor(ls[0], 32);
    float lt1 = ls[1] + __shfl_xor(ls[1], 32);
    if (lh == 0) { linv[w][0][lq] = 1.f/lt0; linv[w][1][lq] = 1.f/lt1; }

#pragma unroll
    for (int g2 = 0; g2 < 2; ++g2)
#pragma unroll
        for (int r = 0; r < 16; ++r) {
            const int qr = (r&3) + 8*(r>>2) + 4*lh;
            const float inv = linv[w][g2][qr];
            const size_t o = ((size_t)(b*NSEQ) + qt*64 + g2*32 + qr)*DIMM + head*HDIM + lq;
            float v0 = O[g2][0][r]*inv, v1 = O[g2][1][r]*inv;
            unsigned short h0 = f2bf(v0), h1 = f2bf(v1);
            aoh[o]      = h0;  aol[o]      = f2bf(v0 - bf2f(h0));
            aoh[o + 32] = h1;  aol[o + 32] = f2bf(v1 - bf2f(h1));
        }
}

// ---------------------------------------------------------------------------
// gemm2_grp: out = ao @ w_out + b_out, split-2 (3-term), REGISTER-ONLY.
// 2 waves per block sharing the B hi/lo streams (same n0, different m0) ->
// L1 sharing cuts B traffic in half (204 -> 153 MB total). Per-wave code
// byte-identical to the proven gemm2_reg. grid (64, 7), block 128 -> 448
// blocks keeps every CU covered.
// ---------------------------------------------------------------------------
__global__ __launch_bounds__(128, 2)
void gemm2_grp(const unsigned short* __restrict__ Ah, const unsigned short* __restrict__ Al,
               const unsigned short* __restrict__ Bh, const unsigned short* __restrict__ Bl,
               const float* __restrict__ bias, float* __restrict__ out)
{
    const int tid = threadIdx.x;
    const int w = tid >> 6, lane = tid & 63;
    const int lq = lane & 31, lh = lane >> 5;
    const int m0 = (blockIdx.x*2 + w) * 64;
    const int n0 = blockIdx.y * 64;
    const unsigned short* aBh = Ah + (size_t)(m0 + lq)*KDIM + lh*8;
    const unsigned short* aBl = Al + (size_t)(m0 + lq)*KDIM + lh*8;
    const unsigned short* bBh = Bh + (size_t)(n0 + lq)*KDIM + lh*8;
    const unsigned short* bBl = Bl + (size_t)(n0 + lq)*KDIM + lh*8;

    floatx16 acc[2][2] = {};
    short8 aH[2][2][2], aL[2][2][2], bH[2][2][2], bL[2][2][2];
#define LD2(kt, par) {                                                        \
    _Pragma("unroll") for (int fm = 0; fm < 2; ++fm)                          \
    _Pragma("unroll") for (int c = 0; c < 2; ++c) {                           \
        const size_t off = (size_t)fm*32*KDIM + (kt)*32 + c*16;               \
        aH[par][fm][c] = *(const short8*)(aBh + off);                         \
        aL[par][fm][c] = *(const short8*)(aBl + off);                         \
        bH[par][fm][c] = *(const short8*)(bBh + off);                         \
        bL[par][fm][c] = *(const short8*)(bBl + off); } }

    LD2(0, 0)
#pragma unroll
    for (int kt = 0; kt < 14; ++kt) {
        const int par = kt & 1;
        if (kt < 13) LD2(kt+1, par^1)
#pragma unroll
        for (int c = 0; c < 2; ++c)
#pragma unroll
            for (int fm = 0; fm < 2; ++fm)
#pragma unroll
                for (int fn = 0; fn < 2; ++fn) {
                    acc[fm][fn] = MFMA32(aH[par][fm][c], bH[par][fn][c], acc[fm][fn]);
                    acc[fm][fn] = MFMA32(aL[par][fm][c], bH[par][fn][c], acc[fm][fn]);
                    acc[fm][fn] = MFMA32(aH[par][fm][c], bL[par][fn][c], acc[fm][fn]);
                }
    }
#undef LD2

#pragma unroll
    for (int fm = 0; fm < 2; ++fm)
#pragma unroll
        for (int fn = 0; fn < 2; ++fn) {
            const int gn = n0 + fn*32 + lq;
            const float bv = bias[gn];
#pragma unroll
            for (int r = 0; r < 16; ++r) {
                const int gm = m0 + fm*32 + (r&3) + 8*(r>>2) + 4*lh;
                out[(size_t)gm*DIMM + gn] = acc[fm][fn][r] + bv;
            }
        }
}

// ---------------------------------------------------------------------------
extern "C" void kernel_launch(void* const* d_in, const int* in_sizes, int n_in,
                              void* d_out, int out_size, void* d_ws, size_t ws_size,
                              hipStream_t stream)
{
    const float* x    = (const float*)d_in[0];
    const float* wqv  = (const float*)d_in[1];
    const float* ek   = (const float*)d_in[2];
    const float* eb   = (const float*)d_in[3];
    const float* wout = (const float*)d_in[4];
    const float* bout = (const float*)d_in[5];
    float* out = (float*)d_out;

    const size_t MK = (size_t)MROWS*KDIM;        // 3,670,016
    const size_t EK = (size_t)NHEAD*NSEQ*HDIM;   // 458,752
    unsigned short* p = (unsigned short*)d_ws;
    unsigned short* xh    = p;  p += MK;
    unsigned short* wqvTh = p;  p += (size_t)896*KDIM;
    unsigned short* woTh  = p;  p += (size_t)512*KDIM;
    unsigned short* woTl  = p;  p += (size_t)512*KDIM;
    unsigned short* ekh   = p;  p += EK;
    unsigned short* qh    = p;  p += MK;
    unsigned short* vTh   = p;  p += MK;
    unsigned short* bp    = p;  p += (size_t)NHEAD*NSEQ*NSEQ;  // fp16
    unsigned short* aoh   = p;  p += MK;
    unsigned short* aol   = p;  p += MK;

    prep_all<<<6132, 256, 0, stream>>>(x, ek, wqv, wout, eb,
                                       xh, ekh, wqvTh, woTh, woTl, bp);
    gemm1_grp<<<dim3(32, 14), 256, 0, stream>>>(xh, wqvTh, qh, vTh);
    attn7s<<<224, 256, 0, stream>>>(qh, vTh, ekh, bp, aoh, aol);
    gemm2_grp<<<dim3(64, 7), 128, 0, stream>>>(aoh, aol, woTh, woTl, bout, out);
}

// Round 7
// 185.994 us; speedup vs baseline: 1.2983x; 1.0744x over previous
//
#include <hip/hip_runtime.h>
#include <hip/hip_bf16.h>
#include <hip/hip_fp16.h>

#define BATCH 8
#define NSEQ 1024
#define DIMM 448
#define NHEAD 7
#define HDIM 64
#define MROWS (BATCH*NSEQ)   // 8192
#define KDIM 448
#define SCALE_F 0.125f

typedef short short8 __attribute__((ext_vector_type(8)));
typedef float floatx16 __attribute__((ext_vector_type(16)));

#define MFMA32(a,b,c) __builtin_amdgcn_mfma_f32_32x32x16_bf16(a,b,c,0,0,0)

__device__ __forceinline__ unsigned short f2bf(float f){
    __hip_bfloat16 h = __float2bfloat16(f);
    return *reinterpret_cast<unsigned short*>(&h);
}
__device__ __forceinline__ float bf2f(unsigned short u){
    __hip_bfloat16 h; *reinterpret_cast<unsigned short*>(&h) = u;
    return __bfloat162float(h);
}
__device__ __forceinline__ float h2f(unsigned short u){
    __half h; *reinterpret_cast<unsigned short*>(&h) = u;
    return __half2float(h);
}
__device__ __forceinline__ unsigned short f2h(float f){
    __half h = __float2half(f);
    return *reinterpret_cast<unsigned short*>(&h);
}

// ---------------------------------------------------------------------------
// prep_all: fused conversions (one launch).
//   [0,3584)      : x fp32 -> xh bf16 (1 float4/thread)
//   [3584,4032)   : ek fp32 -> kP bf16, FRAGMENT-PACKED (see below)
//   [4032,4228)   : wqv [448][896] -> wqvTh [896][448] bf16  (4x 64-thr units)
//   [4228,4340)   : wout [448][448] -> woTh/woTl [512][448] split bf16
//   [4340,6132)   : eb -> bp fp16, pre-scaled by 0.125, attn granule order
// kP layout (shorts): ((h*32+mm)*4 + c)*512 + lane*8 + j =
//   ek[h][mm*32 + (lane&31)][c*16 + (lane>>5)*8 + j]
//   -> every attn K load is 64 lanes x 16B CONTIGUOUS (16 cache lines, was 32).
// bp layout: ((((h*16+qt)*32 + mt)*4 + g2*2 + jj)*512 + lane*8 + t) where
//   score q = qt*64 + g2*32 + (lane&31), m = mt*32 + (t&3)+8*(t>>2)+16*jj+4*(lane>>5)
// ---------------------------------------------------------------------------
__global__ __launch_bounds__(256)
void prep_all(const float* __restrict__ x, const float* __restrict__ ek,
              const float* __restrict__ wqv, const float* __restrict__ wout,
              const float* __restrict__ eb,
              unsigned short* __restrict__ xh, unsigned short* __restrict__ ekh,
              unsigned short* __restrict__ wqvTh, unsigned short* __restrict__ woTh,
              unsigned short* __restrict__ woTl, unsigned short* __restrict__ bp)
{
    __shared__ float T[2][64][33];
    const int bx = blockIdx.x, tid = threadIdx.x;

    if (bx < 3584) {                         // x -> bf16
        int i = bx*256 + tid;
        float4 v = ((const float4*)x)[i];
        ((ushort4*)xh)[i] = make_ushort4(f2bf(v.x), f2bf(v.y), f2bf(v.z), f2bf(v.w));
    } else if (bx < 4032) {                  // ek -> kP (fragment-packed)
        int i = (bx-3584)*256 + tid;         // 0..114687 chunk of 4 shorts
        const int h  = i >> 14, mm = (i >> 9) & 31, c = (i >> 7) & 3;
        const int ln = (i >> 1) & 63, jh = i & 1;
        const float* src = ek + ((size_t)(h*NSEQ) + mm*32 + (ln & 31))*HDIM
                              + c*16 + (ln >> 5)*8 + jh*4;
        float4 v = *(const float4*)src;
        ((ushort4*)ekh)[i] = make_ushort4(f2bf(v.x), f2bf(v.y), f2bf(v.z), f2bf(v.w));
    } else if (bx < 4228) {                  // wqv transpose, single bf16
        int lid = (bx-4032)*4 + (tid>>6);    // 0..783 = kc(56) x ng(14)
        int kc = lid % 56, ng = lid / 56;
        int n = ng*64 + (tid&63);
        unsigned short h[8];
#pragma unroll
        for (int j = 0; j < 8; ++j) h[j] = f2bf(wqv[(size_t)(kc*8+j)*896 + n]);
        size_t o = (size_t)n*KDIM + kc*8;
        *(ushort4*)(wqvTh + o)     = make_ushort4(h[0],h[1],h[2],h[3]);
        *(ushort4*)(wqvTh + o + 4) = make_ushort4(h[4],h[5],h[6],h[7]);
    } else if (bx < 4340) {                  // wout transpose, split hi/lo
        int lid = (bx-4228)*4 + (tid>>6);    // 0..447 = kc(56) x ng(8)
        int kc = lid % 56, ng = lid / 56;
        int n = ng*64 + (tid&63);
        ushort4 h0={0,0,0,0}, h1={0,0,0,0}, l0={0,0,0,0}, l1={0,0,0,0};
        if (n < DIMM) {
            unsigned short h[8], l[8];
#pragma unroll
            for (int j = 0; j < 8; ++j) {
                float f = wout[(size_t)(kc*8+j)*DIMM + n];
                h[j] = f2bf(f); l[j] = f2bf(f - bf2f(h[j]));
            }
            h0 = make_ushort4(h[0],h[1],h[2],h[3]); h1 = make_ushort4(h[4],h[5],h[6],h[7]);
            l0 = make_ushort4(l[0],l[1],l[2],l[3]); l1 = make_ushort4(l[4],l[5],l[6],l[7]);
        }
        size_t o = (size_t)n*KDIM + kc*8;
        *(ushort4*)(woTh + o) = h0; *(ushort4*)(woTh + o + 4) = h1;
        *(ushort4*)(woTl + o) = l0; *(ushort4*)(woTl + o + 4) = l1;
    } else {                                 // bias prep
        const int sub = tid >> 7, st = tid & 127;
        const int lid = (bx-4340)*2 + sub;   // 0..3583
        const int mt = lid & 31, qt = (lid>>5) & 15, h = lid >> 9;
#pragma unroll
        for (int it = 0; it < 4; ++it) {
            int idx = it*128 + st;
            int row = idx >> 3, c4 = (idx & 7)*4;
            float4 v = *(const float4*)(eb + ((size_t)(h*NSEQ + qt*64 + row))*NSEQ + mt*32 + c4);
            T[sub][row][c4+0]=v.x; T[sub][row][c4+1]=v.y;
            T[sub][row][c4+2]=v.z; T[sub][row][c4+3]=v.w;
        }
        __syncthreads();
        const int g2 = st >> 6, lane = st & 63;
        const int lq = lane & 31, quad = lane >> 5;
        const int q = g2*32 + lq;
        unsigned short* dst = bp + ((((size_t)h*16 + qt)*32 + mt)*4 + g2*2)*512 + lane*8;
#pragma unroll
        for (int jj = 0; jj < 2; ++jj) {
            unsigned short o[8];
#pragma unroll
            for (int t = 0; t < 8; ++t) {
                int m = (t&3) + 8*(t>>2) + 16*jj + 4*quad;
                o[t] = f2h(T[sub][q][m] * SCALE_F);
            }
            *(ushort4*)(dst + jj*512)     = make_ushort4(o[0],o[1],o[2],o[3]);
            *(ushort4*)(dst + jj*512 + 4) = make_ushort4(o[4],o[5],o[6],o[7]);
        }
    }
}

// ---------------------------------------------------------------------------
// gemm1_grp: qv = x @ w_qv, single bf16, REGISTER-ONLY per wave.
// 4 waves per block, same n0 (y), different m0 -> B-tile L1-shared.
// v-heads epilogue now writes vP FRAGMENT-PACKED (shorts):
//   ((bh*32 + mm)*4 + u)*512 + lane*8 + j =
//   V[b][h][m = mm*32 + ((u>>1)*2 + (lane>>5))*8 + j][d = (lane&31) + (u&1)*32]
// -> every attn V load is 64 lanes x 16B contiguous; also turns this
//    epilogue's 16x 2B scatter into 4x 8B stores per fragment.
// grid (32, 14), block 256.
// ---------------------------------------------------------------------------
__global__ __launch_bounds__(256, 2)
void gemm1_grp(const unsigned short* __restrict__ Ah, const unsigned short* __restrict__ Bh,
               unsigned short* __restrict__ qd, unsigned short* __restrict__ vTd)
{
    const int tid = threadIdx.x;
    const int w = tid >> 6, lane = tid & 63;
    const int lq = lane & 31, lh = lane >> 5;
    const int m0 = (blockIdx.x*4 + w) * 64;
    const int y  = blockIdx.y;
    const int n0 = y * 64;
    const unsigned short* aB = Ah + (size_t)(m0 + lq)*KDIM + lh*8;
    const unsigned short* bB = Bh + (size_t)(n0 + lq)*KDIM + lh*8;

    floatx16 acc[2][2] = {};
    short8 aR[2][2][2], bR[2][2][2];
#define LD1(kt, par) {                                                        \
    _Pragma("unroll") for (int fm = 0; fm < 2; ++fm)                          \
    _Pragma("unroll") for (int c = 0; c < 2; ++c) {                           \
        aR[par][fm][c] = *(const short8*)(aB + (size_t)fm*32*KDIM + (kt)*32 + c*16); \
        bR[par][fm][c] = *(const short8*)(bB + (size_t)fm*32*KDIM + (kt)*32 + c*16); } }

    LD1(0, 0)
#pragma unroll
    for (int kt = 0; kt < 14; ++kt) {
        const int par = kt & 1;
        if (kt < 13) LD1(kt+1, par^1)
#pragma unroll
        for (int c = 0; c < 2; ++c)
#pragma unroll
            for (int fm = 0; fm < 2; ++fm)
#pragma unroll
                for (int fn = 0; fn < 2; ++fn)
                    acc[fm][fn] = MFMA32(aR[par][fm][c], bR[par][fn][c], acc[fm][fn]);
    }
#undef LD1

    if (y < NHEAD) {
#pragma unroll
        for (int fm = 0; fm < 2; ++fm)
#pragma unroll
            for (int fn = 0; fn < 2; ++fn) {
                const int d = fn*32 + lq;
#pragma unroll
                for (int r = 0; r < 16; ++r) {
                    const int gm = m0 + fm*32 + (r&3) + 8*(r>>2) + 4*lh;
                    const int b = gm >> 10, ns = gm & 1023;
                    qd[((size_t)((b*NHEAD + y)*NSEQ + ns))*HDIM + d] = f2bf(acc[fm][fn][r]);
                }
            }
    } else {
        const int head = y - NHEAD;
#pragma unroll
        for (int fm = 0; fm < 2; ++fm) {
            const int gm0 = m0 + fm*32;
            const int b = gm0 >> 10, mm = (gm0 & 1023) >> 5;
            unsigned short* base = vTd + ((size_t)((b*NHEAD + head)*32 + mm))*2048;
#pragma unroll
            for (int fn = 0; fn < 2; ++fn)
#pragma unroll
                for (int rq = 0; rq < 4; ++rq) {
                    const int u = (rq>>1)*2 + fn;
                    const int lanep = (rq&1)*32 + lq;
                    *(ushort4*)(base + u*512 + lanep*8 + 4*lh) = make_ushort4(
                        f2bf(acc[fm][fn][rq*4+0]), f2bf(acc[fm][fn][rq*4+1]),
                        f2bf(acc[fm][fn][rq*4+2]), f2bf(acc[fm][fn][rq*4+3]));
                }
        }
    }
}

// ---------------------------------------------------------------------------
// attn7p: attn7 (proven 44.2us, no setprio) with FRAGMENT-PACKED K and V.
// Theory: attn is vector-memory PIPE-THROUGHPUT bound (MfmaUtil 11 + VALU 18
// + HBM 10 + Occ 8 at 44us): each old K/V load touched 32 cache lines (lanes
// spanned 32 rows); packed layouts make all 12 PREF loads 64x16B contiguous
// (16 lines), cutting line-transactions/SEC/wave ~320 -> ~192.
// Structure identical to attn7: 4 waves b-sharing b-indep K/bias via L1,
// 64 q-rows/wave, 32 m-tiles, depth-1 reg ping-pong, wave-private pS,
// no barriers. Bijective XCD swizzle (224 = 8*28). grid 224, block 256.
// ---------------------------------------------------------------------------
__global__ __launch_bounds__(256, 2)
void attn7p(const unsigned short* __restrict__ qh_g, const unsigned short* __restrict__ vTh,
            const unsigned short* __restrict__ ekh, const unsigned short* __restrict__ bp,
            unsigned short* __restrict__ aoh, unsigned short* __restrict__ aol)
{
    __shared__ unsigned short pS[4][1024];   // per-wave P transpose (8KB)
    __shared__ float linv[4][2][32];         // per-wave 1/l

    const int tid = threadIdx.x;
    const int w = tid >> 6, lane = tid & 63;
    const int lq = lane & 31, lh = lane >> 5;

    // bijective XCD swizzle: 224 blocks, 28 per XCD
    const int orig = blockIdx.x;
    const int wg = (orig & 7)*28 + (orig >> 3);
    const int bq = wg & 1, qt = (wg >> 1) & 15, head = wg >> 5;
    const int b = bq*4 + w;
    const int bh = b*NHEAD + head;

    short8 qf[2][4];
#pragma unroll
    for (int g2 = 0; g2 < 2; ++g2)
#pragma unroll
        for (int c = 0; c < 4; ++c)
            qf[g2][c] = *(const short8*)(qh_g +
                ((size_t)(bh*NSEQ) + qt*64 + g2*32 + lq)*HDIM + c*16 + lh*8);

    const unsigned short* kB = ekh + (size_t)head*65536 + lane*8;             // b-indep, packed
    const unsigned short* vB = vTh + (size_t)bh*65536 + lane*8;               // per-b, packed
    const unsigned short* bB = bp + ((size_t)(head*16 + qt))*65536 + lane*8;  // b-indep, packed

    short8 kR[2][4], vR[2][4], bR[2][4];
#define PREF(J, par) { const int mm = ((J) < 32) ? (J) : 0;                    \
    _Pragma("unroll") for (int c = 0; c < 4; ++c)                              \
        kR[par][c] = *(const short8*)(kB + (size_t)mm*2048 + c*512);           \
    _Pragma("unroll") for (int u = 0; u < 4; ++u)                              \
        vR[par][u] = *(const short8*)(vB + (size_t)mm*2048 + u*512);           \
    _Pragma("unroll") for (int u = 0; u < 4; ++u)                              \
        bR[par][u] = *(const short8*)(bB + (size_t)mm*2048 + u*512); }

    floatx16 O[2][2] = {};
    float ls[2] = {0.f, 0.f};

#define SEC(J, par, nxt) {                                                     \
    PREF((J)+1, nxt)                                                           \
    _Pragma("unroll") for (int g2 = 0; g2 < 2; ++g2) {                         \
        floatx16 S = {};                                                       \
        _Pragma("unroll") for (int c = 0; c < 4; ++c)                          \
            S = MFMA32(kR[par][c], qf[g2][c], S);                              \
        _Pragma("unroll") for (int g = 0; g < 4; ++g) {                        \
            unsigned short hb[4];                                              \
            _Pragma("unroll") for (int j2 = 0; j2 < 4; ++j2) {                 \
                const int i = g*4 + j2;                                        \
                float bs = h2f((unsigned short)bR[par][g2*2 + (i>>3)][i&7]);   \
                float pv = __expf(fmaf(S[i], SCALE_F, bs));                    \
                ls[g2] += pv;  hb[j2] = f2bf(pv);                              \
            }                                                                  \
            *(ushort4*)(pS[w] + g*256 + lq*8 + lh*4) = make_ushort4(hb[0],hb[1],hb[2],hb[3]); \
        }                                                                      \
        _Pragma("unroll") for (int c2 = 0; c2 < 2; ++c2) {                     \
            short8 pf = *(const short8*)(pS[w] + ((c2*2+lh)*32 + lq)*8);       \
            O[g2][0] = MFMA32(pf, vR[par][c2*2+0], O[g2][0]);                  \
            O[g2][1] = MFMA32(pf, vR[par][c2*2+1], O[g2][1]);                  \
        } } }

    PREF(0, 0)
    for (int jj = 0; jj < 16; ++jj) {
        SEC(2*jj,   0, 1)
        SEC(2*jj+1, 1, 0)
    }
#undef SEC
#undef PREF

    // l: partial per lane-column -> full via lh-partner, transpose via LDS
    float lt0 = ls[0] + __shfl_xor(ls[0], 32);
    float lt1 = ls[1] + __shfl_xor(ls[1], 32);
    if (lh == 0) { linv[w][0][lq] = 1.f/lt0; linv[w][1][lq] = 1.f/lt1; }

#pragma unroll
    for (int g2 = 0; g2 < 2; ++g2)
#pragma unroll
        for (int r = 0; r < 16; ++r) {
            const int qr = (r&3) + 8*(r>>2) + 4*lh;
            const float inv = linv[w][g2][qr];
            const size_t o = ((size_t)(b*NSEQ) + qt*64 + g2*32 + qr)*DIMM + head*HDIM + lq;
            float v0 = O[g2][0][r]*inv, v1 = O[g2][1][r]*inv;
            unsigned short h0 = f2bf(v0), h1 = f2bf(v1);
            aoh[o]      = h0;  aol[o]      = f2bf(v0 - bf2f(h0));
            aoh[o + 32] = h1;  aol[o + 32] = f2bf(v1 - bf2f(h1));
        }
}

// ---------------------------------------------------------------------------
// gemm2_grp: out = ao @ w_out + b_out, split-2 (3-term), REGISTER-ONLY.
// 2 waves per block sharing the B hi/lo streams. grid (64, 7), block 128.
// ---------------------------------------------------------------------------
__global__ __launch_bounds__(128, 2)
void gemm2_grp(const unsigned short* __restrict__ Ah, const unsigned short* __restrict__ Al,
               const unsigned short* __restrict__ Bh, const unsigned short* __restrict__ Bl,
               const float* __restrict__ bias, float* __restrict__ out)
{
    const int tid = threadIdx.x;
    const int w = tid >> 6, lane = tid & 63;
    const int lq = lane & 31, lh = lane >> 5;
    const int m0 = (blockIdx.x*2 + w) * 64;
    const int n0 = blockIdx.y * 64;
    const unsigned short* aBh = Ah + (size_t)(m0 + lq)*KDIM + lh*8;
    const unsigned short* aBl = Al + (size_t)(m0 + lq)*KDIM + lh*8;
    const unsigned short* bBh = Bh + (size_t)(n0 + lq)*KDIM + lh*8;
    const unsigned short* bBl = Bl + (size_t)(n0 + lq)*KDIM + lh*8;

    floatx16 acc[2][2] = {};
    short8 aH[2][2][2], aL[2][2][2], bH[2][2][2], bL[2][2][2];
#define LD2(kt, par) {                                                        \
    _Pragma("unroll") for (int fm = 0; fm < 2; ++fm)                          \
    _Pragma("unroll") for (int c = 0; c < 2; ++c) {                           \
        const size_t off = (size_t)fm*32*KDIM + (kt)*32 + c*16;               \
        aH[par][fm][c] = *(const short8*)(aBh + off);                         \
        aL[par][fm][c] = *(const short8*)(aBl + off);                         \
        bH[par][fm][c] = *(const short8*)(bBh + off);                         \
        bL[par][fm][c] = *(const short8*)(bBl + off); } }

    LD2(0, 0)
#pragma unroll
    for (int kt = 0; kt < 14; ++kt) {
        const int par = kt & 1;
        if (kt < 13) LD2(kt+1, par^1)
#pragma unroll
        for (int c = 0; c < 2; ++c)
#pragma unroll
            for (int fm = 0; fm < 2; ++fm)
#pragma unroll
                for (int fn = 0; fn < 2; ++fn) {
                    acc[fm][fn] = MFMA32(aH[par][fm][c], bH[par][fn][c], acc[fm][fn]);
                    acc[fm][fn] = MFMA32(aL[par][fm][c], bH[par][fn][c], acc[fm][fn]);
                    acc[fm][fn] = MFMA32(aH[par][fm][c], bL[par][fn][c], acc[fm][fn]);
                }
    }
#undef LD2

#pragma unroll
    for (int fm = 0; fm < 2; ++fm)
#pragma unroll
        for (int fn = 0; fn < 2; ++fn) {
            const int gn = n0 + fn*32 + lq;
            const float bv = bias[gn];
#pragma unroll
            for (int r = 0; r < 16; ++r) {
                const int gm = m0 + fm*32 + (r&3) + 8*(r>>2) + 4*lh;
                out[(size_t)gm*DIMM + gn] = acc[fm][fn][r] + bv;
            }
        }
}

// ---------------------------------------------------------------------------
extern "C" void kernel_launch(void* const* d_in, const int* in_sizes, int n_in,
                              void* d_out, int out_size, void* d_ws, size_t ws_size,
                              hipStream_t stream)
{
    const float* x    = (const float*)d_in[0];
    const float* wqv  = (const float*)d_in[1];
    const float* ek   = (const float*)d_in[2];
    const float* eb   = (const float*)d_in[3];
    const float* wout = (const float*)d_in[4];
    const float* bout = (const float*)d_in[5];
    float* out = (float*)d_out;

    const size_t MK = (size_t)MROWS*KDIM;        // 3,670,016
    const size_t EK = (size_t)NHEAD*NSEQ*HDIM;   // 458,752
    unsigned short* p = (unsigned short*)d_ws;
    unsigned short* xh    = p;  p += MK;
    unsigned short* wqvTh = p;  p += (size_t)896*KDIM;
    unsigned short* woTh  = p;  p += (size_t)512*KDIM;
    unsigned short* woTl  = p;  p += (size_t)512*KDIM;
    unsigned short* ekh   = p;  p += EK;        // kP: fragment-packed K
    unsigned short* qh    = p;  p += MK;
    unsigned short* vTh   = p;  p += MK;        // vP: fragment-packed V
    unsigned short* bp    = p;  p += (size_t)NHEAD*NSEQ*NSEQ;  // fp16
    unsigned short* aoh   = p;  p += MK;
    unsigned short* aol   = p;  p += MK;

    prep_all<<<6132, 256, 0, stream>>>(x, ek, wqv, wout, eb,
                                       xh, ekh, wqvTh, woTh, woTl, bp);
    gemm1_grp<<<dim3(32, 14), 256, 0, stream>>>(xh, wqvTh, qh, vTh);
    attn7p<<<224, 256, 0, stream>>>(qh, vTh, ekh, bp, aoh, aol);
    gemm2_grp<<<dim3(64, 7), 128, 0, stream>>>(aoh, aol, woTh, woTl, bout, out);
}